// Round 7
// baseline (189.252 us; speedup 1.0000x reference)
//
#include <hip/hip_runtime.h>
#include <hip/hip_cooperative_groups.h>
#include <math.h>

namespace cg = cooperative_groups;

#define H       2048
#define E       64
#define TOKENS  16384
#define BATCH   4
#define NBLK    256
#define TPBTOK  64          // tokens per block

typedef _Float16 f16x8  __attribute__((ext_vector_type(8)));
typedef float    f32x16 __attribute__((ext_vector_type(16)));

// ws float offsets
#define WHI_OFF  0          // 131072 f16 = 65536 floats
#define WLO_OFF  65536      // 131072 f16
#define PART_OFF 131072     // NBLK * 128 floats (psum[64] | cnt[64])

// LDS float offsets (64 KB arena = 16384 floats)
#define FIN_OFF  0          // [64][65] = 4160 floats
#define SC_OFF   4224       // [64][64] = 4096 floats
#define HIST_OFF 8384       // 64 floats

// ---- phase 0: W fp32 -> tiled f16 hi/lo in 32x32x16 B-fragment order ----
// slot s = (kg*2 + et)*64 + sl ; e = et*32 + (sl&31) ; k = kg*16 + (sl>>5)*8 + j
__device__ __forceinline__
void do_wconv(const float* __restrict__ W, _Float16* __restrict__ whi,
              _Float16* __restrict__ wlo, int s)
{
    const int kg = s >> 7;
    const int et = (s >> 6) & 1;
    const int sl = s & 63;
    const int e  = et * 32 + (sl & 31);
    const int kb = kg * 16 + ((sl >> 5) << 3);
    const float4 a = *(const float4*)(W + (size_t)e * H + kb);
    const float4 b = *(const float4*)(W + (size_t)e * H + kb + 4);
    const float xv[8] = {a.x, a.y, a.z, a.w, b.x, b.y, b.z, b.w};
    f16x8 hi, lo;
    #pragma unroll
    for (int j = 0; j < 8; ++j) {
        const _Float16 h = (_Float16)xv[j];
        hi[j] = h;
        lo[j] = (_Float16)(xv[j] - (float)h);
    }
    *(f16x8*)(whi + (size_t)s * 8) = hi;
    *(f16x8*)(wlo + (size_t)s * 8) = lo;
}

// ---- phase 1: gate GEMM + top2/softmax/partials for 64 tokens ----
// waves: tg = w>>2 (token tile of 32), ks = w&3 (K-slice of 512)
__device__ __forceinline__
void do_main(const float* __restrict__ x, const _Float16* __restrict__ whi,
             const _Float16* __restrict__ wlo, float* __restrict__ out,
             float* __restrict__ part, float* lds, int bid, int tid)
{
    const int l  = tid & 63;
    const int w  = tid >> 6;     // 0..7
    const int tg = w >> 2;
    const int ks = w & 3;

    const int    trow = bid * TPBTOK + tg * 32 + (l & 31);   // A row = lane&31
    const float* xb   = x + (size_t)trow * H + ks * 512 + ((l >> 5) << 3);
    const f16x8* bh   = (const f16x8*)whi + (size_t)(ks * 32) * 128 + l;
    const f16x8* blp  = (const f16x8*)wlo + (size_t)(ks * 32) * 128 + l;

    f32x16 acc[2];
    #pragma unroll
    for (int et = 0; et < 2; ++et)
        #pragma unroll
        for (int i = 0; i < 16; ++i) acc[et][i] = 0.f;

    // 2-deep A prefetch, 1-deep B prefetch
    float4 a0c = *(const float4*)xb,        a1c = *(const float4*)(xb + 4);
    float4 a0n = *(const float4*)(xb + 16), a1n = *(const float4*)(xb + 20);
    f16x8 b0h = bh[0],  b1h = bh[64];
    f16x8 b0l = blp[0], b1l = blp[64];

    #pragma unroll
    for (int kk = 0; kk < 32; ++kk) {
        float4 a0nn = a0n, a1nn = a1n;
        if (kk < 30) {
            a0nn = *(const float4*)(xb + (kk + 2) * 16);
            a1nn = *(const float4*)(xb + (kk + 2) * 16 + 4);
        }
        f16x8 nb0h = b0h, nb1h = b1h, nb0l = b0l, nb1l = b1l;
        if (kk < 31) {
            nb0h = bh[(kk + 1) * 128];       nb1h = bh[(kk + 1) * 128 + 64];
            nb0l = blp[(kk + 1) * 128];      nb1l = blp[(kk + 1) * 128 + 64];
        }
        const float xv[8] = {a0c.x, a0c.y, a0c.z, a0c.w, a1c.x, a1c.y, a1c.z, a1c.w};
        f16x8 ahi, alo;
        #pragma unroll
        for (int j = 0; j < 8; ++j) {
            const _Float16 h = (_Float16)xv[j];
            ahi[j] = h;
            alo[j] = (_Float16)(xv[j] - (float)h);
        }
        acc[0] = __builtin_amdgcn_mfma_f32_32x32x16_f16(ahi, b0h, acc[0], 0, 0, 0);
        acc[0] = __builtin_amdgcn_mfma_f32_32x32x16_f16(ahi, b0l, acc[0], 0, 0, 0);
        acc[0] = __builtin_amdgcn_mfma_f32_32x32x16_f16(alo, b0h, acc[0], 0, 0, 0);
        acc[1] = __builtin_amdgcn_mfma_f32_32x32x16_f16(ahi, b1h, acc[1], 0, 0, 0);
        acc[1] = __builtin_amdgcn_mfma_f32_32x32x16_f16(ahi, b1l, acc[1], 0, 0, 0);
        acc[1] = __builtin_amdgcn_mfma_f32_32x32x16_f16(alo, b1h, acc[1], 0, 0, 0);
        a0c = a0n; a1c = a1n; a0n = a0nn; a1n = a1nn;
        b0h = nb0h; b1h = nb1h; b0l = nb0l; b1l = nb1l;
    }

    // write K-slice partials: row=(r&3)+8*(r>>2)+4*(l>>5), col=et*32+(l&31)
    #pragma unroll
    for (int et = 0; et < 2; ++et)
        #pragma unroll
        for (int r = 0; r < 16; ++r) {
            const int row = (r & 3) + 8 * (r >> 2) + 4 * (l >> 5);
            lds[((tg * 4 + ks) * 32 + row) * 64 + et * 32 + (l & 31)] = acc[et][r];
        }
    __syncthreads();

    // reduce over 4 ks: 64 tokens x 64 experts = 4096 outs, 512 thr x 2 reps
    {
        float4 s[2];
        #pragma unroll
        for (int rep = 0; rep < 2; ++rep) {
            const int idx = rep * 512 + tid;
            const int t = idx >> 4, c4 = (idx & 15) * 4;
            const int tg2 = t >> 5, tl = t & 31;
            float4 a4 = make_float4(0.f, 0.f, 0.f, 0.f);
            #pragma unroll
            for (int k2 = 0; k2 < 4; ++k2) {
                const float4 v = *(const float4*)&lds[((tg2 * 4 + k2) * 32 + tl) * 64 + c4];
                a4.x += v.x; a4.y += v.y; a4.z += v.z; a4.w += v.w;
            }
            s[rep] = a4;
        }
        __syncthreads();    // all partial reads done before overwrite
        #pragma unroll
        for (int rep = 0; rep < 2; ++rep) {
            const int idx = rep * 512 + tid;
            const int t = idx >> 4, c4 = (idx & 15) * 4;
            lds[FIN_OFF + t * 65 + c4 + 0] = s[rep].x;
            lds[FIN_OFF + t * 65 + c4 + 1] = s[rep].y;
            lds[FIN_OFF + t * 65 + c4 + 2] = s[rep].z;
            lds[FIN_OFF + t * 65 + c4 + 3] = s[rep].w;
        }
    }
    __syncthreads();

    // top-2 + softmax: waves 0..1, lanes 0..31; token = w*32 + l
    int i1 = 0, i2 = 0;
    if (w < 2 && l < 32) {
        const int tloc = w * 32 + l;
        float lg[64];
        #pragma unroll
        for (int e = 0; e < 64; ++e) lg[e] = lds[FIN_OFF + tloc * 65 + e];
        float v1 = lg[0];
        #pragma unroll
        for (int e = 1; e < 64; ++e) { if (lg[e] > v1) { v1 = lg[e]; i1 = e; } }
        float v2 = -INFINITY;
        #pragma unroll
        for (int e = 0; e < 64; ++e) { if (e != i1 && lg[e] > v2) { v2 = lg[e]; i2 = e; } }
        float den = 0.f;
        #pragma unroll
        for (int e = 0; e < 64; ++e) den += __expf(lg[e] - v1);
        const float inv_den = 1.f / den;
        const float s1 = inv_den;                    // exp(v1-v1)/den
        const float s2 = __expf(v2 - v1) * inv_den;
        const float rs = 1.f / (s1 + s2 + 1e-20f);
        const int gt = bid * TPBTOK + tloc;
        *(float2*)&out[2 * gt]              = make_float2((float)i1, (float)i2);
        *(float2*)&out[2 * TOKENS + 2 * gt] = make_float2(s1 * rs, s2 * rs);
        // scores, rotated columns for conflict-free column sums
        #pragma unroll
        for (int e = 0; e < 64; ++e)
            lds[SC_OFF + tloc * 64 + ((e + tloc) & 63)] = __expf(lg[e] - v1) * inv_den;
    }
    __syncthreads();
    if (w == 0) {
        float cs = 0.f;                  // expert l's score sum over 64 tokens
        #pragma unroll
        for (int r = 0; r < 64; ++r) cs += lds[SC_OFF + r * 64 + ((l + r) & 63)];
        part[bid * 128 + l] = cs;
        lds[HIST_OFF + l] = 0.f;
    }
    __syncthreads();
    if (w < 2 && l < 32) {
        atomicAdd(&lds[HIST_OFF + i1], 1.f);
        atomicAdd(&lds[HIST_OFF + i2], 1.f);
    }
    __syncthreads();
    if (w == 0) part[bid * 128 + 64 + l] = lds[HIST_OFF + l];
}

// ---- phase 2: aux-loss reduction over NBLK per-block partials ----
__device__ __forceinline__
void do_aux(const float* __restrict__ part, float* __restrict__ out,
            float* lds, int tid)
{
    const int half = tid >> 8;          // 0..1 splits the j range
    const int be   = tid & 255;
    const int b = be >> 6, e = be & 63;
    float ps = 0.f, ct = 0.f;
    #pragma unroll 4
    for (int j = half * 32; j < half * 32 + 32; ++j) {   // 64 blocks per batch
        const int base = (b * 64 + j) * 128;
        ps += part[base + e];           // coalesced across e
        ct += part[base + 64 + e];
    }
    lds[tid]       = ps;
    lds[512 + tid] = ct;
    __syncthreads();
    if (tid < 256) {
        const float psf = lds[tid] + lds[tid + 256];
        const float ctf = lds[512 + tid] + lds[512 + tid + 256];
        // ce = ctf * E/(S*k); meanprob = psf/S
        float val = ctf * (64.0f / (4096.0f * 2.0f)) * (psf / 4096.0f);
        #pragma unroll
        for (int off = 32; off > 0; off >>= 1) val += __shfl_xor(val, off, 64);
        if ((tid & 63) == 0) lds[1024 + (tid >> 6)] = val;
    }
    __syncthreads();
    if (tid == 0)
        out[4 * TOKENS] = (lds[1024] + lds[1025] + lds[1026] + lds[1027]) * (0.001f / 4.0f);
}

// ---- fused cooperative kernel: 256 blocks x 512 thr (1 block/CU guaranteed) ----
__global__ __launch_bounds__(512, 2)
void router_fused(const float* __restrict__ x, const float* __restrict__ W,
                  float* __restrict__ out, float* __restrict__ ws)
{
    __shared__ float lds[16384];
    _Float16* whi  = (_Float16*)(ws + WHI_OFF);
    _Float16* wlo  = (_Float16*)(ws + WLO_OFF);
    float*    part = ws + PART_OFF;

    cg::grid_group grid = cg::this_grid();

    const int s = blockIdx.x * 512 + threadIdx.x;
    if (s < 16384) do_wconv(W, whi, wlo, s);
    __threadfence();
    grid.sync();

    do_main(x, whi, wlo, out, part, lds, blockIdx.x, threadIdx.x);
    __threadfence();
    grid.sync();

    if (blockIdx.x == 0) do_aux(part, out, lds, threadIdx.x);
}

// ---- fallback (non-cooperative) path: same phases, 3 dispatches ----
__global__ __launch_bounds__(512)
void wconv_k(const float* __restrict__ W, _Float16* __restrict__ whi,
             _Float16* __restrict__ wlo)
{
    do_wconv(W, whi, wlo, blockIdx.x * 512 + threadIdx.x);
}

__global__ __launch_bounds__(512, 2)
void main_k(const float* __restrict__ x, const _Float16* __restrict__ whi,
            const _Float16* __restrict__ wlo, float* __restrict__ out,
            float* __restrict__ part)
{
    __shared__ float lds[16384];
    do_main(x, whi, wlo, out, part, lds, blockIdx.x, threadIdx.x);
}

__global__ __launch_bounds__(512)
void aux_k(const float* __restrict__ part, float* __restrict__ out)
{
    __shared__ float lds[1056];
    do_aux(part, out, lds, threadIdx.x);
}

extern "C" void kernel_launch(void* const* d_in, const int* in_sizes, int n_in,
                              void* d_out, int out_size, void* d_ws, size_t ws_size,
                              hipStream_t stream)
{
    (void)in_sizes; (void)n_in; (void)out_size; (void)ws_size;
    const float* x = (const float*)d_in[0];
    const float* W = (const float*)d_in[1];
    float* out = (float*)d_out;
    float* ws  = (float*)d_ws;

    _Float16* whi  = (_Float16*)(ws + WHI_OFF);
    _Float16* wlo  = (_Float16*)(ws + WLO_OFF);
    float*    part = ws + PART_OFF;

    void* args[] = {(void*)&x, (void*)&W, (void*)&out, (void*)&ws};
    hipError_t err = hipLaunchCooperativeKernel((const void*)router_fused,
                                                dim3(NBLK), dim3(512), args, 0, stream);
    if (err != hipSuccess) {
        // deterministic fallback: same phases as 3 plain dispatches
        hipLaunchKernelGGL(wconv_k, dim3(32), dim3(512), 0, stream, W, whi, wlo);
        hipLaunchKernelGGL(main_k, dim3(NBLK), dim3(512), 0, stream, x, whi, wlo, out, part);
        hipLaunchKernelGGL(aux_k, dim3(1), dim3(512), 0, stream, part, out);
    }
}

// Round 8
// 89.592 us; speedup vs baseline: 2.1124x; 2.1124x over previous
//
#include <hip/hip_runtime.h>
#include <math.h>

#define H       2048
#define E       64
#define TOKENS  16384
#define BATCH   4
#define NBLK    512

typedef _Float16 f16x8  __attribute__((ext_vector_type(8)));
typedef float    f32x16 __attribute__((ext_vector_type(16)));

// ws float offsets
#define WHI_OFF  0          // 131072 f16 = 65536 floats
#define WLO_OFF  65536      // 131072 f16
#define PART_OFF 131072     // NBLK * 128 floats (psum[64] | cnt[64])
#define TICK_OFF 196608     // 1 uint ticket

// ---- W fp32 -> tiled f16 hi/lo in 32x32x16 B-fragment order (proven) ----
// slot s = (kg*2 + et)*64 + l ; e = et*32 + (l&31) ; k = kg*16 + (l>>5)*8 + j
__global__ __launch_bounds__(256)
void wconv(const float* __restrict__ W, _Float16* __restrict__ whi,
           _Float16* __restrict__ wlo, unsigned* __restrict__ ticket)
{
    const int s  = blockIdx.x * 256 + threadIdx.x;   // 0..16383
    const int kg = s >> 7;          // 0..127 (K=16 group)
    const int et = (s >> 6) & 1;    // expert tile 0..1
    const int l  = s & 63;
    const int e  = et * 32 + (l & 31);
    const int kb = kg * 16 + ((l >> 5) << 3);
    const float4 a = *(const float4*)(W + (size_t)e * H + kb);
    const float4 b = *(const float4*)(W + (size_t)e * H + kb + 4);
    const float xv[8] = {a.x, a.y, a.z, a.w, b.x, b.y, b.z, b.w};
    f16x8 hi, lo;
    #pragma unroll
    for (int j = 0; j < 8; ++j) {
        const _Float16 h = (_Float16)xv[j];
        hi[j] = h;
        lo[j] = (_Float16)(xv[j] - (float)h);
    }
    *(f16x8*)(whi + (size_t)s * 8) = hi;
    *(f16x8*)(wlo + (size_t)s * 8) = lo;
    if (s == 0) *ticket = 0u;       // reset last-block ticket for the next dispatch
}

// ---- main: 512 blocks x 512 thr (2 blocks/CU, 4 waves/SIMD) + fused aux tail ----
// wave = ks 0..7 (K-slice of 256); each wave: 32 tokens x 64 experts via 2x mfma_32x32x16
__global__ __launch_bounds__(512, 4)
void router_main(const float* __restrict__ x,
                 const _Float16* __restrict__ whi,
                 const _Float16* __restrict__ wlo,
                 float* __restrict__ out,
                 float* __restrict__ part,
                 unsigned* __restrict__ ticket)
{
    __shared__ float lds[16384];   // 64 KB: [8 ks][32 t][64 e] partials, then reused
    __shared__ unsigned lastf;

    const int tid = threadIdx.x;
    const int l   = tid & 63;
    const int ks  = tid >> 6;      // 0..7

    const int    trow = blockIdx.x * 32 + (l & 31);          // A row = lane&31
    const float* xb   = x + (size_t)trow * H + ks * 256 + ((l >> 5) << 3);
    const f16x8* bh   = (const f16x8*)whi + (size_t)(ks * 16) * 128 + l;  // 128 slots per kg
    const f16x8* blp  = (const f16x8*)wlo + (size_t)(ks * 16) * 128 + l;

    f32x16 acc[2];
    #pragma unroll
    for (int et = 0; et < 2; ++et)
        #pragma unroll
        for (int i = 0; i < 16; ++i) acc[et][i] = 0.f;

    float4 a0 = *(const float4*)xb;
    float4 a1 = *(const float4*)(xb + 4);
    f16x8 b0h = bh[0],  b1h = bh[64];
    f16x8 b0l = blp[0], b1l = blp[64];

    #pragma unroll
    for (int kk = 0; kk < 16; ++kk) {
        float4 n0 = a0, n1 = a1;
        f16x8 nb0h = b0h, nb1h = b1h, nb0l = b0l, nb1l = b1l;
        if (kk < 15) {   // prefetch next step (A from L3/HBM, B from L1/L2)
            n0   = *(const float4*)(xb + (kk + 1) * 16);
            n1   = *(const float4*)(xb + (kk + 1) * 16 + 4);
            nb0h = bh[(kk + 1) * 128];       nb1h = bh[(kk + 1) * 128 + 64];
            nb0l = blp[(kk + 1) * 128];      nb1l = blp[(kk + 1) * 128 + 64];
        }
        const float xv[8] = {a0.x, a0.y, a0.z, a0.w, a1.x, a1.y, a1.z, a1.w};
        f16x8 ahi, alo;
        #pragma unroll
        for (int j = 0; j < 8; ++j) {
            const _Float16 h = (_Float16)xv[j];
            ahi[j] = h;
            alo[j] = (_Float16)(xv[j] - (float)h);
        }
        acc[0] = __builtin_amdgcn_mfma_f32_32x32x16_f16(ahi, b0h, acc[0], 0, 0, 0);
        acc[0] = __builtin_amdgcn_mfma_f32_32x32x16_f16(ahi, b0l, acc[0], 0, 0, 0);
        acc[0] = __builtin_amdgcn_mfma_f32_32x32x16_f16(alo, b0h, acc[0], 0, 0, 0);
        acc[1] = __builtin_amdgcn_mfma_f32_32x32x16_f16(ahi, b1h, acc[1], 0, 0, 0);
        acc[1] = __builtin_amdgcn_mfma_f32_32x32x16_f16(ahi, b1l, acc[1], 0, 0, 0);
        acc[1] = __builtin_amdgcn_mfma_f32_32x32x16_f16(alo, b1h, acc[1], 0, 0, 0);
        a0 = n0; a1 = n1;
        b0h = nb0h; b1h = nb1h; b0l = nb0l; b1l = nb1l;
    }

    // ---- write K-slice partials: row=(r&3)+8*(r>>2)+4*(l>>5), col=et*32+(l&31)
    #pragma unroll
    for (int et = 0; et < 2; ++et)
        #pragma unroll
        for (int r = 0; r < 16; ++r) {
            const int row = (r & 3) + 8 * (r >> 2) + 4 * (l >> 5);
            lds[(ks * 32 + row) * 64 + et * 32 + (l & 31)] = acc[et][r];
        }
    __syncthreads();

    // ---- reduce over 8 ks (512 thr: t=tid>>4, c4=(tid&15)*4), write [32][65]
    {
        const int t = tid >> 4, c4 = (tid & 15) * 4;
        float s0 = 0.f, s1 = 0.f, s2 = 0.f, s3 = 0.f;
        #pragma unroll
        for (int k2 = 0; k2 < 8; ++k2) {
            const float4 v = *(const float4*)&lds[(k2 * 32 + t) * 64 + c4];
            s0 += v.x; s1 += v.y; s2 += v.z; s3 += v.w;
        }
        __syncthreads();    // all partial reads done before overwrite
        lds[t * 65 + c4 + 0] = s0;
        lds[t * 65 + c4 + 1] = s1;
        lds[t * 65 + c4 + 2] = s2;
        lds[t * 65 + c4 + 3] = s3;
    }
    __syncthreads();

    // ---- wave-0 epilogue: lanes 0..31 = tokens (proven serial structure)
    const int w = tid >> 6;
    #define SC_OFF   2112
    #define HIST_OFF 6272
    int i1 = 0, i2 = 0;
    if (w == 0 && l < 32) {
        float lg[64];
        #pragma unroll
        for (int e = 0; e < 64; ++e) lg[e] = lds[l * 65 + e];
        float v1 = lg[0];
        #pragma unroll
        for (int e = 1; e < 64; ++e) { if (lg[e] > v1) { v1 = lg[e]; i1 = e; } }
        float v2 = -INFINITY;
        #pragma unroll
        for (int e = 0; e < 64; ++e) { if (e != i1 && lg[e] > v2) { v2 = lg[e]; i2 = e; } }
        float den = 0.f;
        #pragma unroll
        for (int e = 0; e < 64; ++e) den += __expf(lg[e] - v1);
        const float inv_den = 1.f / den;
        const float s1 = inv_den;                    // exp(v1-v1)/den
        const float s2 = __expf(v2 - v1) * inv_den;
        const float rs = 1.f / (s1 + s2 + 1e-20f);
        const int gt = blockIdx.x * 32 + l;
        *(float2*)&out[2 * gt]              = make_float2((float)i1, (float)i2);
        *(float2*)&out[2 * TOKENS + 2 * gt] = make_float2(s1 * rs, s2 * rs);
        // scores, rotated columns for conflict-free column sums
        #pragma unroll
        for (int e = 0; e < 64; ++e)
            lds[SC_OFF + l * 64 + ((e + l) & 63)] = __expf(lg[e] - v1) * inv_den;
    }
    __syncthreads();
    if (w == 0) {
        float cs = 0.f;                  // expert l's score sum over 32 tokens
        #pragma unroll
        for (int r = 0; r < 32; ++r) cs += lds[SC_OFF + r * 64 + ((l + r) & 63)];
        part[blockIdx.x * 128 + l] = cs;
        lds[HIST_OFF + l] = 0.f;
    }
    __syncthreads();
    if (w == 0 && l < 32) {
        atomicAdd(&lds[HIST_OFF + i1], 1.f);
        atomicAdd(&lds[HIST_OFF + i2], 1.f);
    }
    __syncthreads();
    if (w == 0) part[blockIdx.x * 128 + 64 + l] = lds[HIST_OFF + l];

    // ======== fused aux tail: last block (ticket) reduces all partials ========
    __syncthreads();                 // all part[] stores complete (vmcnt drained)
    if (tid == 0) {
        __threadfence();             // release: write back local L2 (part lines -> L3)
        const unsigned old = atomicAdd(ticket, 1u);
        lastf = (old == NBLK - 1u) ? 1u : 0u;
    }
    __syncthreads();
    if (lastf) {                     // block-uniform branch
        __threadfence();             // acquire: invalidate local L2
        volatile const float* vp = part;   // sc0 loads bypass L1
        const int half = tid >> 8;         // 0..1 splits j-range
        const int be   = tid & 255;
        const int b = be >> 6, e = be & 63;
        float ps = 0.f, ct = 0.f;
        for (int j = half * 64; j < half * 64 + 64; ++j) {   // 128 blocks per batch
            const int base = (b * 128 + j) * 128;
            ps += vp[base + e];
            ct += vp[base + 64 + e];
        }
        lds[tid]       = ps;
        lds[512 + tid] = ct;
        __syncthreads();
        if (tid < 256) {
            const float psf = lds[tid] + lds[tid + 256];
            const float ctf = lds[512 + tid] + lds[512 + tid + 256];
            // ce = ctf * E/(S*k); meanprob = psf/S
            float val = ctf * (64.0f / (4096.0f * 2.0f)) * (psf / 4096.0f);
            #pragma unroll
            for (int off = 32; off > 0; off >>= 1) val += __shfl_xor(val, off, 64);
            if ((tid & 63) == 0) lds[1024 + (tid >> 6)] = val;
        }
        __syncthreads();
        if (tid == 0)
            out[4 * TOKENS] = (lds[1024] + lds[1025] + lds[1026] + lds[1027]) * (0.001f / 4.0f);
    }
}

extern "C" void kernel_launch(void* const* d_in, const int* in_sizes, int n_in,
                              void* d_out, int out_size, void* d_ws, size_t ws_size,
                              hipStream_t stream)
{
    (void)in_sizes; (void)n_in; (void)out_size; (void)ws_size;
    const float* x = (const float*)d_in[0];
    const float* W = (const float*)d_in[1];
    float* out = (float*)d_out;
    float* ws  = (float*)d_ws;

    _Float16* whi    = (_Float16*)(ws + WHI_OFF);
    _Float16* wlo    = (_Float16*)(ws + WLO_OFF);
    float*    part   = ws + PART_OFF;
    unsigned* ticket = (unsigned*)(ws + TICK_OFF);

    hipLaunchKernelGGL(wconv, dim3(64), dim3(256), 0, stream, W, whi, wlo, ticket);
    hipLaunchKernelGGL(router_main, dim3(NBLK), dim3(512), 0, stream,
                       x, whi, wlo, out, part, ticket);
}

// Round 9
// 50.653 us; speedup vs baseline: 3.7362x; 1.7687x over previous
//
#include <hip/hip_runtime.h>
#include <math.h>

#define H       2048
#define E       64
#define TOKENS  16384
#define BATCH   4
#define NBLK    512

typedef _Float16 f16x8  __attribute__((ext_vector_type(8)));
typedef float    f32x16 __attribute__((ext_vector_type(16)));

// ws float offsets
#define WHI_OFF  0          // 131072 f16 = 65536 floats
#define WLO_OFF  65536      // 131072 f16
#define PART_OFF 131072     // NBLK * 128 floats (psum[64] | cnt[64])

// ---- W fp32 -> tiled f16 hi/lo in 32x32x16 B-fragment order (proven) ----
// slot s = (kg*2 + et)*64 + l ; e = et*32 + (l&31) ; k = kg*16 + (l>>5)*8 + j
__global__ __launch_bounds__(256)
void wconv(const float* __restrict__ W, _Float16* __restrict__ whi,
           _Float16* __restrict__ wlo)
{
    const int s  = blockIdx.x * 256 + threadIdx.x;   // 0..16383
    const int kg = s >> 7;
    const int et = (s >> 6) & 1;
    const int l  = s & 63;
    const int e  = et * 32 + (l & 31);
    const int kb = kg * 16 + ((l >> 5) << 3);
    const float4 a = *(const float4*)(W + (size_t)e * H + kb);
    const float4 b = *(const float4*)(W + (size_t)e * H + kb + 4);
    const float xv[8] = {a.x, a.y, a.z, a.w, b.x, b.y, b.z, b.w};
    f16x8 hi, lo;
    #pragma unroll
    for (int j = 0; j < 8; ++j) {
        const _Float16 h = (_Float16)xv[j];
        hi[j] = h;
        lo[j] = (_Float16)(xv[j] - (float)h);
    }
    *(f16x8*)(whi + (size_t)s * 8) = hi;
    *(f16x8*)(wlo + (size_t)s * 8) = lo;
}

// ---- main: 512 blocks x 512 thr (2 blocks/CU); wave = ks (K-slice of 256) ----
// A path: coalesced global -> regs -> per-wave-private swizzled LDS dbuf -> ds_read_b128
__global__ __launch_bounds__(512, 4)
void router_main(const float* __restrict__ x,
                 const _Float16* __restrict__ whi,
                 const _Float16* __restrict__ wlo,
                 float* __restrict__ out,
                 float* __restrict__ part)
{
    __shared__ float lds[16384];   // 64 KB: staging arena, then partials, then epilogue

    const int tid = threadIdx.x;
    const int l   = tid & 63;
    const int ks  = tid >> 6;      // 0..7
    const int t0  = blockIdx.x * 32;

    // --- staging geometry (per-wave-private 8 KB = 2 bufs x 1024 floats) ---
    const int wbase = ks * 2048;
    const int srow  = l >> 3;                 // row-in-group 0..7
    const int su    = (l & 7) ^ srow;         // XOR-swizzled source unit
    const float* xsrc = x + (size_t)(t0 + srow) * H + ks * 256 + su * 4;
    // instr i stages row t = i*8+srow; LDS float idx = wbase+buf+i*256+l*4
    // LDS[t][slot] holds x[t][unit = slot ^ (t&7)]

    // --- fragment-read geometry ---
    const int tA   = l & 31;                  // A row = lane&31
    const int rb   = wbase + tA * 32;
    const int hi5  = l >> 5;                  // 0/1
    const int rsw  = tA & 7;                  // read-side XOR

    const f16x8* bhp = (const f16x8*)whi + (size_t)(ks * 16) * 128 + l;
    const f16x8* blp = (const f16x8*)wlo + (size_t)(ks * 16) * 128 + l;

    f32x16 acc[2];
    #pragma unroll
    for (int et = 0; et < 2; ++et)
        #pragma unroll
        for (int i = 0; i < 16; ++i) acc[et][i] = 0.f;

    float4 g[4];
    // prologue: stage chunk 0 into buf0, load chunk 1 into regs
    #pragma unroll
    for (int i = 0; i < 4; ++i) g[i] = *(const float4*)(xsrc + (size_t)i * 8 * H);
    #pragma unroll
    for (int i = 0; i < 4; ++i) *(float4*)&lds[wbase + i * 256 + l * 4] = g[i];
    #pragma unroll
    for (int i = 0; i < 4; ++i) g[i] = *(const float4*)(xsrc + (size_t)i * 8 * H + 32);

    // B current (kk_lin = 0)
    f16x8 bh0 = bhp[0], bh1 = bhp[64], bl0 = blp[0], bl1 = blp[64];

    #pragma unroll
    for (int c = 0; c < 8; ++c) {
        const int buf = (c & 1) * 1024;
        // write-late: stage chunk c+1 (regs were loaded one iter ago)
        if (c + 1 < 8) {
            const int obuf = ((c + 1) & 1) * 1024;
            #pragma unroll
            for (int i = 0; i < 4; ++i)
                *(float4*)&lds[wbase + obuf + i * 256 + l * 4] = g[i];
        }
        // load-early: chunk c+2 -> regs (global latency hidden under this chunk)
        if (c + 2 < 8) {
            #pragma unroll
            for (int i = 0; i < 4; ++i)
                g[i] = *(const float4*)(xsrc + (size_t)i * 8 * H + (c + 2) * 32);
        }
        #pragma unroll
        for (int kkl = 0; kkl < 2; ++kkl) {
            const int kk_lin = c * 2 + kkl;
            // prefetch next-kk B (L1/L2-hot)
            f16x8 nh0 = bh0, nh1 = bh1, nl0 = bl0, nl1 = bl1;
            if (kk_lin < 15) {
                nh0 = bhp[(kk_lin + 1) * 128];      nh1 = bhp[(kk_lin + 1) * 128 + 64];
                nl0 = blp[(kk_lin + 1) * 128];      nl1 = blp[(kk_lin + 1) * 128 + 64];
            }
            // A fragment from swizzled LDS
            const int u0 = kkl * 4 + hi5 * 2;
            const float4 xa = *(const float4*)&lds[rb + buf + ((u0    ) ^ rsw) * 4];
            const float4 xb = *(const float4*)&lds[rb + buf + ((u0 + 1) ^ rsw) * 4];
            const float xv[8] = {xa.x, xa.y, xa.z, xa.w, xb.x, xb.y, xb.z, xb.w};
            f16x8 ahi, alo;
            #pragma unroll
            for (int j = 0; j < 8; ++j) {
                const _Float16 h = (_Float16)xv[j];
                ahi[j] = h;
                alo[j] = (_Float16)(xv[j] - (float)h);
            }
            acc[0] = __builtin_amdgcn_mfma_f32_32x32x16_f16(ahi, bh0, acc[0], 0, 0, 0);
            acc[0] = __builtin_amdgcn_mfma_f32_32x32x16_f16(ahi, bl0, acc[0], 0, 0, 0);
            acc[0] = __builtin_amdgcn_mfma_f32_32x32x16_f16(alo, bh0, acc[0], 0, 0, 0);
            acc[1] = __builtin_amdgcn_mfma_f32_32x32x16_f16(ahi, bh1, acc[1], 0, 0, 0);
            acc[1] = __builtin_amdgcn_mfma_f32_32x32x16_f16(ahi, bl1, acc[1], 0, 0, 0);
            acc[1] = __builtin_amdgcn_mfma_f32_32x32x16_f16(alo, bh1, acc[1], 0, 0, 0);
            bh0 = nh0; bh1 = nh1; bl0 = nl0; bl1 = nl1;
        }
    }

    // ---- write K-slice partials into this wave's own arena region (no hazard)
    // row=(r&3)+8*(r>>2)+4*(l>>5), col=et*32+(l&31)
    #pragma unroll
    for (int et = 0; et < 2; ++et)
        #pragma unroll
        for (int r = 0; r < 16; ++r) {
            const int row = (r & 3) + 8 * (r >> 2) + 4 * hi5;
            lds[(ks * 32 + row) * 64 + et * 32 + (l & 31)] = acc[et][r];
        }
    __syncthreads();

    // ---- reduce over 8 ks (512 thr: t=tid>>4, c4=(tid&15)*4), write [32][65]
    {
        const int t = tid >> 4, c4 = (tid & 15) * 4;
        float s0 = 0.f, s1 = 0.f, s2 = 0.f, s3 = 0.f;
        #pragma unroll
        for (int k2 = 0; k2 < 8; ++k2) {
            const float4 v = *(const float4*)&lds[(k2 * 32 + t) * 64 + c4];
            s0 += v.x; s1 += v.y; s2 += v.z; s3 += v.w;
        }
        __syncthreads();    // all partial reads done before overwrite
        lds[t * 65 + c4 + 0] = s0;
        lds[t * 65 + c4 + 1] = s1;
        lds[t * 65 + c4 + 2] = s2;
        lds[t * 65 + c4 + 3] = s3;
    }
    __syncthreads();

    // ---- wave-0 epilogue: lanes 0..31 = tokens (proven serial structure)
    const int w = tid >> 6;
    #define SC_OFF   2112
    #define HIST_OFF 6272
    int i1 = 0, i2 = 0;
    if (w == 0 && l < 32) {
        float lg[64];
        #pragma unroll
        for (int e = 0; e < 64; ++e) lg[e] = lds[l * 65 + e];
        float v1 = lg[0];
        #pragma unroll
        for (int e = 1; e < 64; ++e) { if (lg[e] > v1) { v1 = lg[e]; i1 = e; } }
        float v2 = -INFINITY;
        #pragma unroll
        for (int e = 0; e < 64; ++e) { if (e != i1 && lg[e] > v2) { v2 = lg[e]; i2 = e; } }
        float den = 0.f;
        #pragma unroll
        for (int e = 0; e < 64; ++e) den += __expf(lg[e] - v1);
        const float inv_den = 1.f / den;
        const float s1 = inv_den;                    // exp(v1-v1)/den
        const float s2 = __expf(v2 - v1) * inv_den;
        const float rs = 1.f / (s1 + s2 + 1e-20f);
        const int gt = blockIdx.x * 32 + l;
        *(float2*)&out[2 * gt]              = make_float2((float)i1, (float)i2);
        *(float2*)&out[2 * TOKENS + 2 * gt] = make_float2(s1 * rs, s2 * rs);
        // scores, rotated columns for conflict-free column sums
        #pragma unroll
        for (int e = 0; e < 64; ++e)
            lds[SC_OFF + l * 64 + ((e + l) & 63)] = __expf(lg[e] - v1) * inv_den;
    }
    __syncthreads();
    if (w == 0) {
        float cs = 0.f;                  // expert l's score sum over 32 tokens
        #pragma unroll
        for (int r = 0; r < 32; ++r) cs += lds[SC_OFF + r * 64 + ((l + r) & 63)];
        part[blockIdx.x * 128 + l] = cs;
        lds[HIST_OFF + l] = 0.f;
    }
    __syncthreads();
    if (w == 0 && l < 32) {
        atomicAdd(&lds[HIST_OFF + i1], 1.f);
        atomicAdd(&lds[HIST_OFF + i2], 1.f);
    }
    __syncthreads();
    if (w == 0) part[blockIdx.x * 128 + 64 + l] = lds[HIST_OFF + l];
}

// ---- aux loss finalize: reduce 512 per-block partials ----
__global__ __launch_bounds__(256)
void router_aux(const float* __restrict__ part, float* __restrict__ out)
{
    const int tid = threadIdx.x;    // 256 = BATCH*E
    const int b = tid >> 6, e = tid & 63;
    float ps = 0.f, ct = 0.f;
    for (int j = 0; j < 128; ++j) {          // 128 blocks per batch
        const int base = (b * 128 + j) * 128;
        ps += part[base + e];                // coalesced: lanes -> consecutive e
        ct += part[base + 64 + e];
    }
    // ce = ct * E/(S*k); meanprob = ps/S
    float val = ct * (64.0f / (4096.0f * 2.0f)) * (ps / 4096.0f);
    #pragma unroll
    for (int off = 32; off > 0; off >>= 1) val += __shfl_xor(val, off, 64);
    __shared__ float red[4];
    if ((tid & 63) == 0) red[tid >> 6] = val;
    __syncthreads();
    if (tid == 0)
        out[4 * TOKENS] = (red[0] + red[1] + red[2] + red[3]) * (0.001f / 4.0f);
}

extern "C" void kernel_launch(void* const* d_in, const int* in_sizes, int n_in,
                              void* d_out, int out_size, void* d_ws, size_t ws_size,
                              hipStream_t stream)
{
    (void)in_sizes; (void)n_in; (void)out_size; (void)ws_size;
    const float* x = (const float*)d_in[0];
    const float* W = (const float*)d_in[1];
    float* out = (float*)d_out;
    float* ws  = (float*)d_ws;

    _Float16* whi  = (_Float16*)(ws + WHI_OFF);
    _Float16* wlo  = (_Float16*)(ws + WLO_OFF);
    float*    part = ws + PART_OFF;

    hipLaunchKernelGGL(wconv, dim3(64), dim3(256), 0, stream, W, whi, wlo);
    hipLaunchKernelGGL(router_main, dim3(NBLK), dim3(512), 0, stream,
                       x, whi, wlo, out, part);
    hipLaunchKernelGGL(router_aux, dim3(1), dim3(256), 0, stream, part, out);
}